// Round 12
// baseline (170.766 us; speedup 1.0000x reference)
//
#include <hip/hip_runtime.h>
#include <hip/hip_bf16.h>
#include <stdint.h>

#define T_TOKENS 8192
#define D_DIM 1024
#define H_DIM 2048
#define N_EXPERTS 8

typedef __attribute__((ext_vector_type(8))) short bf16x8;
typedef __attribute__((ext_vector_type(8))) unsigned short u16x8;
typedef __attribute__((ext_vector_type(4))) float f32x4;

typedef __attribute__((address_space(1))) const void* gptr_t;
typedef __attribute__((address_space(3))) void* lptr_t;

__device__ __forceinline__ unsigned short f2bf(float f) {
  union { float f; unsigned int u; } x; x.f = f;
  unsigned int r = x.u + 0x7FFFu + ((x.u >> 16) & 1u);
  return (unsigned short)(r >> 16);
}
__device__ __forceinline__ float bf2f(unsigned short b) {
  union { unsigned int u; float f; } x; x.u = ((unsigned int)b) << 16;
  return x.f;
}

__device__ __forceinline__ void gload16(const void* g, void* l) {
  __builtin_amdgcn_global_load_lds((gptr_t)g, (lptr_t)l, 16, 0, 0);
}

// Sync discipline (rule #18)
#define SBAR()  do { __builtin_amdgcn_s_barrier(); __builtin_amdgcn_sched_barrier(0); } while (0)
#define LGKM0() do { asm volatile("s_waitcnt lgkmcnt(0)" ::: "memory"); __builtin_amdgcn_sched_barrier(0); } while (0)
#define VMW(n)  do { __builtin_amdgcn_sched_barrier(0); asm volatile("s_waitcnt vmcnt(" #n ")" ::: "memory"); } while (0)

// ---------------------------------------------------------------------------
// fp32 -> bf16 conversion, single launch (best measured; at the 240MB/6.3TB/s
// roofline ~35-38us). blocks [0,4096)->x; [4096,12288)->w_up; rest->w_down.
// ---------------------------------------------------------------------------
__global__ void cvt_region(const float* __restrict__ x, const float* __restrict__ wu,
                           const float* __restrict__ wd,
                           unsigned short* __restrict__ xb, unsigned short* __restrict__ wub,
                           unsigned short* __restrict__ wdb) {
  const int b = blockIdx.x;
  const float* src; unsigned short* dst; int rb;
  if (b < 4096)        { src = x;  dst = xb;  rb = b; }
  else if (b < 12288)  { src = wu; dst = wub; rb = b - 4096; }
  else                 { src = wd; dst = wdb; rb = b - 12288; }
  const size_t off = ((size_t)rb * 256 + threadIdx.x) * 8;
  const float4 v0 = *reinterpret_cast<const float4*>(src + off);
  const float4 v1 = *reinterpret_cast<const float4*>(src + off + 4);
  u16x8 o;
  o[0] = f2bf(v0.x); o[1] = f2bf(v0.y); o[2] = f2bf(v0.z); o[3] = f2bf(v0.w);
  o[4] = f2bf(v1.x); o[5] = f2bf(v1.y); o[6] = f2bf(v1.z); o[7] = f2bf(v1.w);
  *reinterpret_cast<u16x8*>(dst + off) = o;
}

// ---------------------------------------------------------------------------
// Grouped GEMM — R5's proven interior, ring 4 -> 3 slots for OCCUPANCY 2/CU:
// C[M,N] = A[M,K] @ B[e][N,K]^T. BM=256 BN=128, 8 waves 4Mx2N (64x64/wave).
// K processed in 32-col chunks h=0..2K/64-1; LDS ring-3 per-chunk slots:
// lA 3x[256][32] (48KB) + lB 3x[128][32] (24KB) = 72KB; VGPR ~108 -> with
// __launch_bounds__(512,4): 2 blocks/CU (R5's 96KB allowed only 1; its ~50%
// wait had nothing to hide under — m114: cross-block overlap absorbs it).
// Race-free ladder (invariant: chunk h+1 FORCED at phase h, one barrier
// before its reads):
//   prologue: STAGE(0->s0); STAGE(1->s1); VMW(3); SBAR  [forces chunk 0]
//   phase h:  G_RD(h%3); STAGE(h+2 -> (h+2)%3); VMW(3); LGKM0; MM; SBAR
//     - VMW(3) leaves only stage(h+2) outstanding => forces h+1 (own);
//       end-SBAR makes it global => phase h+1 reads are safe (all waves).
//     - WAR: slot (h+2)%3 == slot(h-1); all waves' reads of chunk h-1
//       retired at their LGKM0 before phase h-1's end-SBAR.
//   tails: VMW(0) at phase 2NT-2; none at 2NT-1.
// XOR swizzle (rule #21, measured 0 conflicts): stage global granule
// (lane&3)^((lane>>3)&3) of row lane>>2, LDS dest linear; read granule
// ((lane>>4)^((lane>>1)&3)).
// FUSE=true: O=bf16(relu(bf16(acc))^2) -> OB. FUSE=false: O=f32(bf16(acc)).
// ---------------------------------------------------------------------------
template <int K, int N, bool FUSE>
__global__ __launch_bounds__(512, 4)
void ggemm(const unsigned short* __restrict__ A,
           const unsigned short* __restrict__ B,
           const int* __restrict__ counts,
           unsigned short* __restrict__ OB,
           float* __restrict__ OF) {
  constexpr int NH = K / 32;      // 32-col chunks
  constexpr int NCB = N / 128;
  __shared__ short lA[3 * 8192];  // 3 slots x [256][32]
  __shared__ short lB[3 * 4096];  // 3 slots x [128][32]

  const int tid = threadIdx.x;
  const int wid = tid >> 6, lane = tid & 63;
  const int wr = wid >> 1, wc = wid & 1;
  const int bid = blockIdx.x;
  const int cb = bid % NCB, rb = bid / NCB;
  const int r0 = rb * 256, c0 = cb * 128;

  int csum[N_EXPERTS + 1];
  csum[0] = 0;
  for (int e = 0; e < N_EXPERTS; ++e) csum[e + 1] = csum[e] + counts[e];
  int eLo = 0;
  while (eLo < N_EXPERTS - 1 && csum[eLo + 1] <= r0) ++eLo;
  int eHi = eLo;
  while (eHi < N_EXPERTS - 1 && csum[eHi + 1] < r0 + 256) ++eHi;

  // staging: lane -> row lane>>2 (16 rows/gload line), pre-swizzled granule
  const int srow = lane >> 2;
  const int scol = ((lane & 3) ^ ((lane >> 3) & 3)) * 8;
  const size_t aBase = (size_t)(r0 + wid * 16 + srow) * K + scol;
  const size_t bBase0 = (size_t)(c0 + wid * 16 + srow) * K + scol;
  const int ldsW = wid * 512;
  const int l15 = lane & 15;
  const int l4 = ((lane >> 4) ^ ((lane >> 1) & 3)) * 8;  // swizzled read granule

  for (int e = eLo; e <= eHi; ++e) {
    const unsigned short* Be = B + (size_t)e * N * K;
    f32x4 acc[4][4];
#pragma unroll
    for (int mi = 0; mi < 4; ++mi)
#pragma unroll
      for (int ni = 0; ni < 4; ++ni) acc[mi][ni] = (f32x4){0.f, 0.f, 0.f, 0.f};

// stage K-chunk H into slot S: 3 gloads/wave (A rows 0-127, 128-255; B)
#define STAGE_H(H, S) do { \
    gload16(A + aBase + (size_t)(H) * 32,                  &lA[(S) * 8192 + ldsW]); \
    gload16(A + aBase + (size_t)128 * K + (size_t)(H) * 32, &lA[(S) * 8192 + ldsW + 4096]); \
    gload16(Be + bBase0 + (size_t)(H) * 32,                 &lB[(S) * 4096 + ldsW]); \
  } while (0)
#define G_RD(S) do { \
    _Pragma("unroll") for (int m_ = 0; m_ < 4; ++m_) \
      fa[m_] = *(const bf16x8*)&lA[(S) * 8192 + (wr * 64 + m_ * 16 + l15) * 32 + l4]; \
    _Pragma("unroll") for (int n_ = 0; n_ < 4; ++n_) \
      fb[n_] = *(const bf16x8*)&lB[(S) * 4096 + (wc * 64 + n_ * 16 + l15) * 32 + l4]; \
  } while (0)
#define G_MM() do { \
    __builtin_amdgcn_s_setprio(1); \
    _Pragma("unroll") for (int m_ = 0; m_ < 4; ++m_) \
      _Pragma("unroll") for (int n_ = 0; n_ < 4; ++n_) \
        acc[m_][n_] = __builtin_amdgcn_mfma_f32_16x16x32_bf16(fa[m_], fb[n_], acc[m_][n_], 0, 0, 0); \
    __builtin_amdgcn_s_setprio(0); \
  } while (0)

    STAGE_H(0, 0); STAGE_H(1, 1);
    VMW(3); SBAR();  // chunk 0 forced (own); SBAR makes it global

    int sR = 0, sW = 2;
#pragma unroll 1
    for (int h = 0; h < NH - 2; ++h) {
      bf16x8 fa[4], fb[4];
      G_RD(sR);
      STAGE_H(h + 2, sW);
      VMW(3); LGKM0(); G_MM(); SBAR();
      sR = (sR == 2) ? 0 : sR + 1;
      sW = (sW == 2) ? 0 : sW + 1;
    }
    {  // h = NH-2: no stage; force the last chunk
      bf16x8 fa[4], fb[4];
      G_RD(sR);
      VMW(0); LGKM0(); G_MM(); SBAR();
      sR = (sR == 2) ? 0 : sR + 1;
    }
    {  // h = NH-1
      bf16x8 fa[4], fb[4];
      G_RD(sR);
      LGKM0(); G_MM(); SBAR();
    }

    // epilogue: C/D layout col=lane&15, row=(lane>>4)*4+reg (m89/m91)
    const int segLo = csum[e], segHi = csum[e + 1];
#pragma unroll
    for (int mi = 0; mi < 4; ++mi) {
      const int rowb = r0 + wr * 64 + mi * 16 + ((lane >> 4) << 2);
#pragma unroll
      for (int ni = 0; ni < 4; ++ni) {
        const int col = c0 + wc * 64 + ni * 16 + l15;
#pragma unroll
        for (int r = 0; r < 4; ++r) {
          const int gr = rowb + r;
          if (gr >= segLo && gr < segHi) {
            if (FUSE) {
              float h2 = bf2f(f2bf(acc[mi][ni][r]));
              h2 = h2 > 0.f ? h2 : 0.f;
              OB[(size_t)gr * N + col] = f2bf(h2 * h2);
            } else {
              OF[(size_t)gr * N + col] = bf2f(f2bf(acc[mi][ni][r]));
            }
          }
        }
      }
    }
#undef STAGE_H
#undef G_RD
#undef G_MM
  }
}

extern "C" void kernel_launch(void* const* d_in, const int* in_sizes, int n_in,
                              void* d_out, int out_size, void* d_ws, size_t ws_size,
                              hipStream_t stream) {
  const float* x = (const float*)d_in[0];
  const float* w_up = (const float*)d_in[1];
  const float* w_down = (const float*)d_in[2];
  const int* counts = (const int*)d_in[3];
  float* out = (float*)d_out;

  char* ws = (char*)d_ws;
  unsigned short* xb  = (unsigned short*)(ws);
  unsigned short* wub = (unsigned short*)(ws + (size_t)16 * 1024 * 1024);
  unsigned short* wdb = (unsigned short*)(ws + (size_t)48 * 1024 * 1024);
  unsigned short* hsq = (unsigned short*)(ws + (size_t)80 * 1024 * 1024);

  cvt_region<<<20480, 256, 0, stream>>>(x, w_up, w_down, xb, wub, wdb);

  // GEMM1: hsq = bf16(relu(bf16(x @ w_up^T))^2); grid 32 rb x 16 cb = 512
  ggemm<D_DIM, H_DIM, true>
      <<<(T_TOKENS / 256) * (H_DIM / 128), 512, 0, stream>>>(xb, wub, counts, hsq, nullptr);
  // GEMM2: out = f32(bf16(hsq @ w_down^T)); grid 32 rb x 8 cb = 256
  ggemm<H_DIM, D_DIM, false>
      <<<(T_TOKENS / 256) * (D_DIM / 128), 512, 0, stream>>>(hsq, wdb, counts, nullptr, out);
}